// Round 1
// baseline (201.222 us; speedup 1.0000x reference)
//
#include <hip/hip_runtime.h>

// CSPN step: out[b,h,w] = sum_{t=0..8} patch_t(b,h,w) * kernel[b,t,h,w]
// patch taps = zero-padded 3x3 neighborhood of input; center tap (t=4)
// replaced by input0. iter_weight is unused (reference returns cspn_output).
//
// Shapes: kernel (8,9,352,1216) f32, input/input0 (8,1,352,1216) f32.
// Memory-bound: ~150.6 MB read + 13.7 MB write -> ~26 us floor at 6.3 TB/s.

#define BS 8
#define H  352
#define W  1216
#define HW (H * W)

__global__ __launch_bounds__(256) void cspn_kernel(
    const float* __restrict__ kern,
    const float* __restrict__ in,
    const float* __restrict__ in0,
    float* __restrict__ out)
{
    const int groupsPerImg = HW / 4;        // 107008
    const int total = BS * groupsPerImg;    // 856064
    int idx = blockIdx.x * blockDim.x + threadIdx.x;
    if (idx >= total) return;

    int b   = idx / groupsPerImg;
    int rem = idx - b * groupsPerImg;
    int h   = rem / (W / 4);
    int wg  = rem - h * (W / 4);
    int w0  = wg * 4;

    const float* inb  = in  + (size_t)b * HW;
    const float* in0b = in0 + (size_t)b * HW;
    // kernel base for this (b, h, w0); tap t is +t*HW from here
    const float* kb   = kern + ((size_t)b * 9) * HW + (size_t)h * W + w0;

    float4 acc = {0.f, 0.f, 0.f, 0.f};

    #pragma unroll
    for (int di = -1; di <= 1; ++di) {
        int hh = h + di;
        if (hh < 0 || hh >= H) continue;   // zero-padded rows contribute 0

        const float* row = inb + (size_t)hh * W + w0;
        float4 x   = *(const float4*)row;                 // aligned: w0 % 4 == 0
        float  xm1 = (w0 > 0)     ? row[-1] : 0.f;        // left edge pad
        float  xp4 = (w0 + 4 < W) ? row[4]  : 0.f;        // right edge pad

        // center-column tap values: input0 for di==0 (compile-time after unroll)
        float4 c = x;
        if (di == 0) c = *(const float4*)(in0b + (size_t)h * W + w0);

        float4 l = {xm1, x.x, x.y, x.z};   // tap column j=-1
        float4 r = {x.y, x.z, x.w, xp4};   // tap column j=+1

        int t = (di + 1) * 3;
        float4 k0 = *(const float4*)(kb + (size_t)t       * HW);
        float4 k1 = *(const float4*)(kb + (size_t)(t + 1) * HW);
        float4 k2 = *(const float4*)(kb + (size_t)(t + 2) * HW);

        acc.x += l.x * k0.x + c.x * k1.x + r.x * k2.x;
        acc.y += l.y * k0.y + c.y * k1.y + r.y * k2.y;
        acc.z += l.z * k0.z + c.z * k1.z + r.z * k2.z;
        acc.w += l.w * k0.w + c.w * k1.w + r.w * k2.w;
    }

    *(float4*)(out + (size_t)b * HW + (size_t)h * W + w0) = acc;
}

extern "C" void kernel_launch(void* const* d_in, const int* in_sizes, int n_in,
                              void* d_out, int out_size, void* d_ws, size_t ws_size,
                              hipStream_t stream) {
    const float* kern = (const float*)d_in[0];  // (8,9,352,1216)
    // d_in[1] = iter_weight, unused by the reference's return value
    const float* in   = (const float*)d_in[2];  // (8,1,352,1216)
    const float* in0  = (const float*)d_in[3];  // (8,1,352,1216)
    float* out        = (float*)d_out;          // (8,1,352,1216)

    const int total  = BS * (HW / 4);           // 856064 threads
    const int block  = 256;
    const int grid   = (total + block - 1) / block;  // 3344
    cspn_kernel<<<grid, block, 0, stream>>>(kern, in, in0, out);
}